// Round 7
// baseline (339.600 us; speedup 1.0000x reference)
//
#include <hip/hip_runtime.h>

#define BB 512
#define TT 512
#define KK 9
#define VP1 30001   // V+1 rows in emb
#define BTK ((size_t)BB * TT * KK)

typedef __attribute__((ext_vector_type(8))) short short8;
typedef __attribute__((ext_vector_type(4))) float float4v;
typedef __attribute__((ext_vector_type(4))) int int4v;
typedef __attribute__((ext_vector_type(4))) unsigned int uint4v;

__device__ __forceinline__ float sigm(float x) {
    return __builtin_amdgcn_rcpf(1.0f + __expf(-x));
}
__device__ __forceinline__ float tanh_(float x) {
    return 1.0f - 2.0f * __builtin_amdgcn_rcpf(__expf(2.0f * x) + 1.0f);
}

__device__ __forceinline__ unsigned short f2bf(float f) {
    unsigned int u = __float_as_uint(f);
    unsigned int r = u + 0x7fffu + ((u >> 16) & 1u);
    return (unsigned short)(r >> 16);
}
__device__ __forceinline__ float bflo2f(unsigned int d) { return __uint_as_float(d << 16); }
__device__ __forceinline__ float bfhi2f(unsigned int d) { return __uint_as_float(d & 0xffff0000u); }

// pack two f32 -> two bf16 (RNE), low16 = a, high16 = b. 1 VALU op.
__device__ __forceinline__ unsigned int cvtpk_bf16(float a, float b) {
    unsigned int r;
    asm("v_cvt_pk_bf16_f32 %0, %1, %2" : "=v"(r) : "v"(a), "v"(b));
    return r;
}

// swap adjacent lanes (l ^ 1) via DPP quad_perm [1,0,3,2] — 1 VALU op, no LDS
__device__ __forceinline__ float dpp_swap1(float x) {
    return __int_as_float(__builtin_amdgcn_mov_dpp(__float_as_int(x), 0xB1, 0xF, 0xF, true));
}

// broadcast lane i's float via SGPR
__device__ __forceinline__ float bcast(float v, int i) {
    return __uint_as_float(__builtin_amdgcn_readlane(__float_as_uint(v), i));
}

// barrier that does NOT drain vmcnt. 0xC07F = vmcnt(63) expcnt(7) lgkmcnt(0).
__device__ __forceinline__ void block_sync_lds() {
    __builtin_amdgcn_s_waitcnt(0xC07F);
    __builtin_amdgcn_s_barrier();
}

// ---------------------------------------------------------------------------
// embW[v][c] (bf16) = emb[v,:] @ W[:,col(c)] + b[col(c)], c-map as before:
// c = dir*256 + u*4 + g -> col = g*64 + u. B-fragments + bias now built
// DIRECTLY from Wf/Wb/bfv/bbv (L2-hot after first blocks) — wswz kernel and
// its launch gap eliminated. f2bf path identical -> bit-identical output.
// ---------------------------------------------------------------------------
__global__ __launch_bounds__(256, 1)
void embw_kernel(const float* __restrict__ emb,
                 const float* __restrict__ Wf, const float* __restrict__ bfv,
                 const float* __restrict__ Wb, const float* __restrict__ bbv,
                 unsigned short* __restrict__ embw)
{
    const int v0 = blockIdx.x * 64;
    const int tid = threadIdx.x;
    const int w = tid >> 6, lane = tid & 63;
    const int l16 = lane & 15, quad = lane >> 4;

    __shared__ __align__(16) unsigned short clds[64][520];

    // B fragments + bias straight from global weights
    short8 bFr[8][2];
    float biasn[8];
#pragma unroll
    for (int n = 0; n < 8; ++n) {
        int c = w * 128 + n * 16 + l16;
        int dirc = c >> 8, rem = c & 255;
        int uu = rem >> 2, g = rem & 3;
        const float* Wp = (dirc ? Wb : Wf) + g * 64 + uu;   // + k*256
        biasn[n] = (dirc ? bbv : bfv)[g * 64 + uu];
#pragma unroll
        for (int q = 0; q < 2; ++q) {
            short8 v;
#pragma unroll
            for (int j = 0; j < 8; ++j) {
                int k = q * 32 + quad * 8 + j;
                v[j] = (short)f2bf(Wp[k * 256]);
            }
            bFr[n][q] = v;
        }
    }

    // A fragments (emb rows, f32 -> bf16 via packed cvt)
    short8 aFr[4][2];
#pragma unroll
    for (int mt = 0; mt < 4; ++mt) {
        int vrow = v0 + mt * 16 + l16;
        if (vrow >= VP1) vrow = VP1 - 1;
        const float* er = emb + (size_t)vrow * 64;
#pragma unroll
        for (int q = 0; q < 2; ++q) {
            const float* p = er + q * 32 + quad * 8;
            float4 x0 = *(const float4*)(p);
            float4 x1 = *(const float4*)(p + 4);
            uint4v pk;
            pk[0] = cvtpk_bf16(x0.x, x0.y);
            pk[1] = cvtpk_bf16(x0.z, x0.w);
            pk[2] = cvtpk_bf16(x1.x, x1.y);
            pk[3] = cvtpk_bf16(x1.z, x1.w);
            aFr[mt][q] = __builtin_bit_cast(short8, pk);
        }
    }

    float4v acc[4][8];
#pragma unroll
    for (int mt = 0; mt < 4; ++mt)
#pragma unroll
        for (int n = 0; n < 8; ++n) {
            acc[mt][n][0] = biasn[n]; acc[mt][n][1] = biasn[n];
            acc[mt][n][2] = biasn[n]; acc[mt][n][3] = biasn[n];
        }
#pragma unroll
    for (int mt = 0; mt < 4; ++mt)
#pragma unroll
        for (int n = 0; n < 8; ++n) {
            acc[mt][n] = __builtin_amdgcn_mfma_f32_16x16x32_bf16(aFr[mt][0], bFr[n][0], acc[mt][n], 0, 0, 0);
            acc[mt][n] = __builtin_amdgcn_mfma_f32_16x16x32_bf16(aFr[mt][1], bFr[n][1], acc[mt][n], 0, 0, 0);
        }

    // C -> LDS repack, then coalesced stores
#pragma unroll
    for (int mt = 0; mt < 4; ++mt)
#pragma unroll
        for (int n = 0; n < 8; ++n) {
            int cc = w * 128 + n * 16 + l16;
#pragma unroll
            for (int r = 0; r < 4; ++r)
                clds[mt * 16 + quad * 4 + r][cc] = f2bf(acc[mt][n][r]);
        }
    __syncthreads();

#pragma unroll
    for (int it = 0; it < 16; ++it) {
        int idx = it * 256 + tid;
        int row = idx >> 6, chunk = idx & 63;
        if (v0 + row < VP1) {
            uint4 val = *(const uint4*)&clds[row][chunk * 8];
            *(uint4*)(embw + (size_t)(v0 + row) * 512 + chunk * 8) = val;
        }
    }
}

// ---------------------------------------------------------------------------
// Recurrence: 256 blocks x 5 waves (320 thr) = 2 dirs x 128 slices of 4 rows.
// Waves 0-3: compute (wave w owns units w*16..w*16+15, all 4 gates; chain =
// quad, M-rows {0,4,8,12}). Wave 4: dedicated pot wave.
// R7: h-publish via DPP pair-swap + cvt_pk -> even lanes write one packed
// dword (2 units). Write pattern goes from 4 lanes/bank (with same-dword
// serialization) to 2 lanes/bank (free). Otherwise identical to R6.
// Barrier counts: compute 1+512+1 = 514; pot 1+513 = 514. Equal.
// ---------------------------------------------------------------------------
__global__ __launch_bounds__(320, 1)
void rec_kernel(const int* __restrict__ tokens,
                const unsigned short* __restrict__ embw,
                const float* __restrict__ Uf, const float* __restrict__ Ub,
                const float* __restrict__ Wd,
                float* __restrict__ potf, float* __restrict__ potb)
{
    const int blk = blockIdx.x;          // 256 = 2 dirs x 128 groups of 4 rows
    const int dir = blk >> 7;
    const int row0 = (blk & 127) * 4;
    const int tid = threadIdx.x;
    const int wv = tid >> 6;             // 0..3 compute, 4 = pot
    const int lane = tid & 63;
    const int l16 = lane & 15, quad = lane >> 4;

    const float* Up = dir ? Ub : Uf;
    float* pot = dir ? potb : potf;

    __shared__ __align__(16) int tokl[4][TT + 8];
    __shared__ __align__(16) unsigned short hl[2][16][72];

    for (int i = tid; i < 2 * 16 * 72; i += 320)
        ((unsigned short*)hl)[i] = 0;
    // stage tokens TIME-REVERSED for bwd, PRE-SHIFTED to embw byte offsets
    for (int i = tid; i < 4 * TT; i += 320) {
        int r = i >> 9, t = i & 511;
        tokl[r][t] = tokens[(row0 + r) * TT + (dir ? (TT - 1 - t) : t)] << 10;
    }
    if (tid < 32) tokl[tid >> 3][TT + (tid & 7)] = 0;   // pad: benign prefetch

    if (wv < 4) {
        // ================= compute waves =================
        const int w = wv;
        const int u = w * 16 + l16;
        const bool wrLane = ((l16 & 1) == 0);   // even lane publishes the pair

        short8 bU[4][2];
#pragma unroll
        for (int g = 0; g < 4; ++g)
#pragma unroll
            for (int q = 0; q < 2; ++q) {
                short8 v;
#pragma unroll
                for (int j = 0; j < 8; ++j) {
                    int k = q * 32 + quad * 8 + j;
                    v[j] = (short)f2bf(Up[k * 256 + g * 64 + u]);
                }
                bU[g][q] = v;
            }

        __syncthreads();
        __builtin_amdgcn_s_setprio(1);

        const char* ebase = (const char*)((const uint2*)embw + dir * 64 + u);

        // prime: token-offsets t=0..3 and their z prefetch
        int4v tca = *(const int4v*)&tokl[quad][0];
        uint2 zxp[4];
#pragma unroll
        for (int d = 0; d < 4; ++d)
            zxp[d] = *(const uint2*)(ebase + tca[d]);

        float c_st = 0.f, h_st = 0.f;
        float4v accA[4], accB[4];
        const float4v zz = {0.f, 0.f, 0.f, 0.f};
#pragma unroll
        for (int g = 0; g < 4; ++g) { accA[g] = zz; accB[g] = zz; }

        for (int sb = 0; sb < TT; sb += 4) {
            int4v tnx = *(const int4v*)&tokl[quad][sb + 4];
#pragma unroll
            for (int ss = 0; ss < 4; ++ss) {
                const int tcur = tca[ss];
                const uint2 zcur = zxp[ss];

                // ---- pre-barrier: publish h pair (dpp + cvt_pk + 1 dword) ----
                {
                    float hp = dpp_swap1(h_st);
                    if (wrLane)
                        *(unsigned int*)&hl[ss & 1][quad * 4][u] = cvtpk_bf16(h_st, hp);
                }

                // acc z-inits ride the barrier wait
                accA[0][0] = bflo2f(zcur.x);
                accA[1][0] = bfhi2f(zcur.x);
                accA[2][0] = bflo2f(zcur.y);
                accA[3][0] = bfhi2f(zcur.y);

                block_sync_lds();

                const unsigned short* hrow = &hl[ss & 1][l16][0];
                short8 a0 = *(const short8*)(hrow + quad * 8);
                short8 a1 = *(const short8*)(hrow + 32 + quad * 8);

                // off-chain: prefetch z for t = sb+ss+4 (addr math fills
                // the lgkm wait shadow before the MFMAs)
                zxp[ss] = *(const uint2*)(ebase + tnx[ss]);

                // issue g=2 (cell, longest gate chain) first, then i, f, o
                accA[2] = __builtin_amdgcn_mfma_f32_16x16x32_bf16(a0, bU[2][0], accA[2], 0, 0, 0);
                accB[2] = __builtin_amdgcn_mfma_f32_16x16x32_bf16(a1, bU[2][1], zz, 0, 0, 0);
                accA[0] = __builtin_amdgcn_mfma_f32_16x16x32_bf16(a0, bU[0][0], accA[0], 0, 0, 0);
                accB[0] = __builtin_amdgcn_mfma_f32_16x16x32_bf16(a1, bU[0][1], zz, 0, 0, 0);
                accA[1] = __builtin_amdgcn_mfma_f32_16x16x32_bf16(a0, bU[1][0], accA[1], 0, 0, 0);
                accB[1] = __builtin_amdgcn_mfma_f32_16x16x32_bf16(a1, bU[1][1], zz, 0, 0, 0);
                accA[3] = __builtin_amdgcn_mfma_f32_16x16x32_bf16(a0, bU[3][0], accA[3], 0, 0, 0);
                accB[3] = __builtin_amdgcn_mfma_f32_16x16x32_bf16(a1, bU[3][1], zz, 0, 0, 0);

                {
                    float zg_ = accA[2][0] + accB[2][0];
                    float tg  = tanh_(zg_);
                    float zi_ = accA[0][0] + accB[0][0];
                    float si  = sigm(zi_);
                    float zf_ = accA[1][0] + accB[1][0];
                    float zo_ = accA[3][0] + accB[3][0];
                    float cn  = sigm(zf_) * c_st + si * tg;
                    float hn  = sigm(zo_) * tanh_(cn);
                    bool m = (tcur != 0);
                    h_st = m ? hn : h_st;
                    c_st = m ? cn : c_st;
                }
            }
            tca = tnx;
        }
        __builtin_amdgcn_s_setprio(0);

        // publish h_511 for the pot wave's final step (s=512 -> buffer 0)
        {
            float hp = dpp_swap1(h_st);
            if (wrLane)
                *(unsigned int*)&hl[0][quad * 4][u] = cvtpk_bf16(h_st, hp);
        }
        block_sync_lds();
    } else {
        // ================= pot wave =================
        short8 bW[2];
#pragma unroll
        for (int q = 0; q < 2; ++q) {
            short8 v;
#pragma unroll
            for (int j = 0; j < 8; ++j) {
                int k = q * 32 + quad * 8 + j;
                v[j] = (l16 < KK) ? (short)f2bf(Wd[(dir * 64 + k) * KK + l16]) : (short)0;
            }
            bW[q] = v;
        }

        __syncthreads();

        int vOff = ((row0 + quad) * TT + (dir ? (TT - 1) : 0)) * KK + l16;
        const int vStep = dir ? -KK : KK;
        const bool potAct = (l16 < KK);
        const float4v zz = {0.f, 0.f, 0.f, 0.f};

        for (int s = 0; s <= TT; ++s) {
            block_sync_lds();
            const unsigned short* hrow = &hl[s & 1][l16][0];
            short8 a0 = *(const short8*)(hrow + quad * 8);
            short8 a1 = *(const short8*)(hrow + 32 + quad * 8);
            if (s > 0) {
                float4v accP;
                accP = __builtin_amdgcn_mfma_f32_16x16x32_bf16(a0, bW[0], zz, 0, 0, 0);
                accP = __builtin_amdgcn_mfma_f32_16x16x32_bf16(a1, bW[1], accP, 0, 0, 0);
                if (potAct) pot[vOff] = accP[0];
                vOff += vStep;
            }
        }
    }
}

// ---------------------------------------------------------------------------
// Fused combine + Viterbi (64-thread proven version). readlane broadcast +
// max3 value-max + equality cascade; padded LDS kills the t+1 guard.
// ---------------------------------------------------------------------------
__global__ __launch_bounds__(64)
void viterbi_kernel(const int* __restrict__ tokens,
                    const float* __restrict__ potf, const float* __restrict__ potb,
                    const float* __restrict__ bd, const float* __restrict__ trans,
                    float* __restrict__ dec_out, float* __restrict__ pot_out,
                    float* __restrict__ seq_out)
{
    const int row = blockIdx.x;
    const int lane = threadIdx.x;

    __shared__ float pl[TT * KK + 16];      // padded: t+1 == TT read is safe
    __shared__ unsigned char bpl[(TT - 1) * KK];
    __shared__ unsigned char maskl[TT + 8]; // padded
    __shared__ unsigned char segmap[64][KK];
    __shared__ unsigned char bseq[65];
    __shared__ float decl_[TT];
    __shared__ float bdl[16];

    if (lane < KK) bdl[lane] = bd[lane];
    if (lane < 8) maskl[TT + lane] = 0;
    pl[TT * KK + lane % 16] = 0.f;

    int cnt = 0;
#pragma unroll
    for (int ch = 0; ch < TT / 64; ++ch) {
        int tk = tokens[row * TT + ch * 64 + lane];
        int m = (tk != 0) ? 1 : 0;
        maskl[ch * 64 + lane] = (unsigned char)m;
        cnt += m;
    }
    for (int off = 32; off > 0; off >>= 1) cnt += __shfl_down(cnt, off);
    if (lane == 0) seq_out[row] = (float)cnt;

    const size_t base = (size_t)row * (TT * KK);
    int r9 = lane % KK;
    for (int i = 0; i < (TT * KK) / 64; ++i) {
        int li = i * 64 + lane;
        float s = potf[base + li] + potb[base + li] + bdl[r9];
        pl[li] = s;
        pot_out[base + li] = s;
        r9 = (r9 + 1 == KK) ? 0 : r9 + 1;
    }
    __syncthreads();

    float treg[KK];
#pragma unroll
    for (int i = 0; i < KK; ++i) treg[i] = (lane < KK) ? trans[i * KK + lane] : 0.f;

    float alpha = (lane < KK) ? pl[lane] : -1e30f;
    float pnext = (lane < KK) ? pl[KK + lane] : 0.f;
    int mnext = maskl[1];
#pragma unroll 4
    for (int t = 1; t < TT; ++t) {
        float p = pnext;
        int m = mnext;
        pnext = (lane < KK) ? pl[(t + 1) * KK + lane] : 0.f;  // pad makes t+1==TT safe
        mnext = maskl[t + 1];

        float sc[KK];
#pragma unroll
        for (int i = 0; i < KK; ++i) sc[i] = bcast(alpha, i) + treg[i];
        float b0 = fmaxf(fmaxf(fmaxf(sc[0], sc[1]), sc[2]),
                   fmaxf(fmaxf(fmaxf(sc[3], sc[4]), sc[5]),
                         fmaxf(fmaxf(sc[6], sc[7]), sc[8])));
        int i0 = 8;
#pragma unroll
        for (int i = 7; i >= 0; --i) i0 = (sc[i] == b0) ? i : i0;

        alpha = m ? (b0 + p) : alpha;
        int bpv = m ? i0 : lane;
        if (lane < KK) bpl[(t - 1) * KK + lane] = (unsigned char)bpv;
    }
    float sc[KK];
#pragma unroll
    for (int i = 0; i < KK; ++i) sc[i] = bcast(alpha, i);
    float b0 = fmaxf(fmaxf(fmaxf(sc[0], sc[1]), sc[2]),
               fmaxf(fmaxf(fmaxf(sc[3], sc[4]), sc[5]),
                     fmaxf(fmaxf(sc[6], sc[7]), sc[8])));
    int last = 8;
#pragma unroll
    for (int i = 7; i >= 0; --i) last = (sc[i] == b0) ? i : last;
    __syncthreads();

    {
        int l = lane;
#pragma unroll
        for (int x = 0; x < KK; ++x) {
            int y = x;
#pragma unroll
            for (int d = 7; d >= 0; --d) {
                int t = 8 * l + d;
                if (t < TT - 1) y = bpl[t * KK + y];
            }
            segmap[l][x] = (unsigned char)y;
        }
    }
    __syncthreads();
    if (lane == 0) {
        int cur = last;
        bseq[64] = (unsigned char)last;
        for (int l = 63; l >= 0; --l) {
            cur = segmap[l][cur];
            bseq[l] = (unsigned char)cur;
        }
    }
    __syncthreads();
    {
        int l = lane;
        int cur = bseq[l + 1];
#pragma unroll
        for (int d = 7; d >= 0; --d) {
            int t = 8 * l + d;
            if (t < TT - 1) cur = bpl[t * KK + cur];
            decl_[t] = (maskl[t] != 0) ? (float)cur : 0.f;
        }
    }
    __syncthreads();
#pragma unroll
    for (int ch = 0; ch < TT / 64; ++ch)
        dec_out[(size_t)row * TT + ch * 64 + lane] = decl_[ch * 64 + lane];
}

extern "C" void kernel_launch(void* const* d_in, const int* in_sizes, int n_in,
                              void* d_out, int out_size, void* d_ws, size_t ws_size,
                              hipStream_t stream)
{
    const int*   tokens = (const int*)d_in[0];
    const float* emb    = (const float*)d_in[1];
    const float* Wf     = (const float*)d_in[2];
    const float* Uf     = (const float*)d_in[3];
    const float* bfv    = (const float*)d_in[4];
    const float* Wb     = (const float*)d_in[5];
    const float* Ub     = (const float*)d_in[6];
    const float* bbv    = (const float*)d_in[7];
    const float* Wd     = (const float*)d_in[8];
    const float* bd     = (const float*)d_in[9];
    const float* trans  = (const float*)d_in[10];

    float* out     = (float*)d_out;
    float* dec_out = out;
    float* pot_out = out + (size_t)BB * TT;
    float* seq_out = out + (size_t)BB * TT + BTK;

    float* potf = (float*)d_ws;
    float* potb = potf + BTK;
    unsigned short* embw = (unsigned short*)(potb + BTK);

    hipLaunchKernelGGL(embw_kernel, dim3(469), dim3(256), 0, stream,
                       emb, Wf, bfv, Wb, bbv, embw);
    hipLaunchKernelGGL(rec_kernel, dim3(256), dim3(320), 0, stream,
                       tokens, embw, Uf, Ub, Wd, potf, potb);
    hipLaunchKernelGGL(viterbi_kernel, dim3(BB), dim3(64), 0, stream,
                       tokens, potf, potb, bd, trans, dec_out, pot_out, seq_out);
}

// Round 8
// 323.909 us; speedup vs baseline: 1.0484x; 1.0484x over previous
//
#include <hip/hip_runtime.h>

#define BB 512
#define TT 512
#define KK 9
#define VP1 30001   // V+1 rows in emb
#define BTK ((size_t)BB * TT * KK)

typedef __attribute__((ext_vector_type(8))) short short8;
typedef __attribute__((ext_vector_type(4))) float float4v;
typedef __attribute__((ext_vector_type(4))) int int4v;
typedef __attribute__((ext_vector_type(4))) unsigned int uint4v;

__device__ __forceinline__ float sigm(float x) {
    return __builtin_amdgcn_rcpf(1.0f + __expf(-x));
}
__device__ __forceinline__ float tanh_(float x) {
    return 1.0f - 2.0f * __builtin_amdgcn_rcpf(__expf(2.0f * x) + 1.0f);
}

__device__ __forceinline__ unsigned short f2bf(float f) {
    unsigned int u = __float_as_uint(f);
    unsigned int r = u + 0x7fffu + ((u >> 16) & 1u);
    return (unsigned short)(r >> 16);
}
__device__ __forceinline__ float bflo2f(unsigned int d) { return __uint_as_float(d << 16); }
__device__ __forceinline__ float bfhi2f(unsigned int d) { return __uint_as_float(d & 0xffff0000u); }

// pack two f32 -> two bf16 (RNE), low16 = a, high16 = b. 1 VALU op.
__device__ __forceinline__ unsigned int cvtpk_bf16(float a, float b) {
    unsigned int r;
    asm("v_cvt_pk_bf16_f32 %0, %1, %2" : "=v"(r) : "v"(a), "v"(b));
    return r;
}

// broadcast lane i's float via SGPR
__device__ __forceinline__ float bcast(float v, int i) {
    return __uint_as_float(__builtin_amdgcn_readlane(__float_as_uint(v), i));
}

// barrier that does NOT drain vmcnt. 0xC07F = vmcnt(63) expcnt(7) lgkmcnt(0).
__device__ __forceinline__ void block_sync_lds() {
    __builtin_amdgcn_s_waitcnt(0xC07F);
    __builtin_amdgcn_s_barrier();
}

// ---------------------------------------------------------------------------
// One-time W swizzle (R0 map): wswz[c][k] = bf16(W_dir[k][g*64+u]),
// c = dir*256 + u*4 + g; bsw[c] = bias. Output aliased onto potf workspace
// (rec writes potf only after embw has consumed wswz).
// ---------------------------------------------------------------------------
__global__ __launch_bounds__(256)
void wswz_kernel(const float* __restrict__ Wf, const float* __restrict__ bfv,
                 const float* __restrict__ Wb, const float* __restrict__ bbv,
                 unsigned short* __restrict__ wswz, float* __restrict__ bsw)
{
    const int tid = threadIdx.x;
#pragma unroll
    for (int it = 0; it < 16; ++it) {
        int o = blockIdx.x * 4096 + it * 256 + tid;   // o = c*64 + k
        int k = o & 63, c = o >> 6;
        int dir = c >> 8, rem = c & 255;
        int u = rem >> 2, g = rem & 3;
        float val = (dir ? Wb : Wf)[k * 256 + g * 64 + u];
        wswz[o] = f2bf(val);
    }
    if (blockIdx.x == 0) {
#pragma unroll
        for (int h = 0; h < 2; ++h) {
            int c = h * 256 + tid;
            int dir = c >> 8, rem = c & 255;
            bsw[c] = (dir ? bbv : bfv)[(rem & 3) * 64 + (rem >> 2)];
        }
    }
}

// ---------------------------------------------------------------------------
// embW[v][c] (bf16) = emb[v,:] @ Wswz[:,c] + bsw[c]. B-frags straight from the
// 64 KB L2-hot wswz table (no per-block staging).
// ---------------------------------------------------------------------------
__global__ __launch_bounds__(256, 1)
void embw_kernel(const float* __restrict__ emb,
                 const unsigned short* __restrict__ wswz, const float* __restrict__ bsw,
                 unsigned short* __restrict__ embw)
{
    const int v0 = blockIdx.x * 64;
    const int tid = threadIdx.x;
    const int w = tid >> 6, lane = tid & 63;
    const int l16 = lane & 15, quad = lane >> 4;

    __shared__ __align__(16) unsigned short clds[64][520];

    // B fragments + bias from global (hot)
    short8 bFr[8][2];
    float biasn[8];
#pragma unroll
    for (int n = 0; n < 8; ++n) {
        int c = w * 128 + n * 16 + l16;
        biasn[n] = bsw[c];
        const unsigned short* wp = wswz + c * 64;
#pragma unroll
        for (int q = 0; q < 2; ++q)
            bFr[n][q] = *(const short8*)(wp + q * 32 + quad * 8);
    }

    // A fragments (emb rows, f32 -> bf16 via packed cvt)
    short8 aFr[4][2];
#pragma unroll
    for (int mt = 0; mt < 4; ++mt) {
        int vrow = v0 + mt * 16 + l16;
        if (vrow >= VP1) vrow = VP1 - 1;
        const float* er = emb + (size_t)vrow * 64;
#pragma unroll
        for (int q = 0; q < 2; ++q) {
            const float* p = er + q * 32 + quad * 8;
            float4 x0 = *(const float4*)(p);
            float4 x1 = *(const float4*)(p + 4);
            uint4v pk;
            pk[0] = cvtpk_bf16(x0.x, x0.y);
            pk[1] = cvtpk_bf16(x0.z, x0.w);
            pk[2] = cvtpk_bf16(x1.x, x1.y);
            pk[3] = cvtpk_bf16(x1.z, x1.w);
            aFr[mt][q] = __builtin_bit_cast(short8, pk);
        }
    }

    float4v acc[4][8];
#pragma unroll
    for (int mt = 0; mt < 4; ++mt)
#pragma unroll
        for (int n = 0; n < 8; ++n) {
            acc[mt][n][0] = biasn[n]; acc[mt][n][1] = biasn[n];
            acc[mt][n][2] = biasn[n]; acc[mt][n][3] = biasn[n];
        }
#pragma unroll
    for (int mt = 0; mt < 4; ++mt)
#pragma unroll
        for (int n = 0; n < 8; ++n) {
            acc[mt][n] = __builtin_amdgcn_mfma_f32_16x16x32_bf16(aFr[mt][0], bFr[n][0], acc[mt][n], 0, 0, 0);
            acc[mt][n] = __builtin_amdgcn_mfma_f32_16x16x32_bf16(aFr[mt][1], bFr[n][1], acc[mt][n], 0, 0, 0);
        }

    // C -> LDS repack, then coalesced stores
#pragma unroll
    for (int mt = 0; mt < 4; ++mt)
#pragma unroll
        for (int n = 0; n < 8; ++n) {
            int cc = w * 128 + n * 16 + l16;
#pragma unroll
            for (int r = 0; r < 4; ++r)
                clds[mt * 16 + quad * 4 + r][cc] = f2bf(acc[mt][n][r]);
        }
    __syncthreads();

#pragma unroll
    for (int it = 0; it < 16; ++it) {
        int idx = it * 256 + tid;
        int row = idx >> 6, chunk = idx & 63;
        if (v0 + row < VP1) {
            uint4 val = *(const uint4*)&clds[row][chunk * 8];
            *(uint4*)(embw + (size_t)(v0 + row) * 512 + chunk * 8) = val;
        }
    }
}

// ---------------------------------------------------------------------------
// Recurrence: 256 blocks x 5 waves (320 thr) = 2 dirs x 128 slices of 4 rows.
// Waves 0-3: compute (wave w owns units w*16..w*16+15, all 4 gates; chain =
// quad, M-rows {0,4,8,12}). Wave 4: dedicated pot wave.
// R6 config (proven best): tokens staged as PRE-SHIFTED byte offsets
// (tok<<10 into embw row); prefetch issued between ds_reads and MFMAs;
// pre-barrier region = cvt_pk + 1 ds_write_b16; setprio(1) on compute waves.
// Barrier counts: compute 1+512+1 = 514; pot 1+513 = 514. Equal.
// ---------------------------------------------------------------------------
__global__ __launch_bounds__(320, 1)
void rec_kernel(const int* __restrict__ tokens,
                const unsigned short* __restrict__ embw,
                const float* __restrict__ Uf, const float* __restrict__ Ub,
                const float* __restrict__ Wd,
                float* __restrict__ potf, float* __restrict__ potb)
{
    const int blk = blockIdx.x;          // 256 = 2 dirs x 128 groups of 4 rows
    const int dir = blk >> 7;
    const int row0 = (blk & 127) * 4;
    const int tid = threadIdx.x;
    const int wv = tid >> 6;             // 0..3 compute, 4 = pot
    const int lane = tid & 63;
    const int l16 = lane & 15, quad = lane >> 4;

    const float* Up = dir ? Ub : Uf;
    float* pot = dir ? potb : potf;

    __shared__ __align__(16) int tokl[4][TT + 8];
    __shared__ __align__(16) unsigned short hl[2][16][72];

    for (int i = tid; i < 2 * 16 * 72; i += 320)
        ((unsigned short*)hl)[i] = 0;
    // stage tokens TIME-REVERSED for bwd, PRE-SHIFTED to embw byte offsets
    for (int i = tid; i < 4 * TT; i += 320) {
        int r = i >> 9, t = i & 511;
        tokl[r][t] = tokens[(row0 + r) * TT + (dir ? (TT - 1 - t) : t)] << 10;
    }
    if (tid < 32) tokl[tid >> 3][TT + (tid & 7)] = 0;   // pad: benign prefetch

    if (wv < 4) {
        // ================= compute waves =================
        const int w = wv;
        const int u = w * 16 + l16;

        short8 bU[4][2];
#pragma unroll
        for (int g = 0; g < 4; ++g)
#pragma unroll
            for (int q = 0; q < 2; ++q) {
                short8 v;
#pragma unroll
                for (int j = 0; j < 8; ++j) {
                    int k = q * 32 + quad * 8 + j;
                    v[j] = (short)f2bf(Up[k * 256 + g * 64 + u]);
                }
                bU[g][q] = v;
            }

        __syncthreads();
        __builtin_amdgcn_s_setprio(1);

        const char* ebase = (const char*)((const uint2*)embw + dir * 64 + u);

        // prime: token-offsets t=0..3 and their z prefetch
        int4v tca = *(const int4v*)&tokl[quad][0];
        uint2 zxp[4];
#pragma unroll
        for (int d = 0; d < 4; ++d)
            zxp[d] = *(const uint2*)(ebase + tca[d]);

        float c_st = 0.f, h_st = 0.f;
        float4v accA[4], accB[4];
        const float4v zz = {0.f, 0.f, 0.f, 0.f};
#pragma unroll
        for (int g = 0; g < 4; ++g) { accA[g] = zz; accB[g] = zz; }

        for (int sb = 0; sb < TT; sb += 4) {
            int4v tnx = *(const int4v*)&tokl[quad][sb + 4];
#pragma unroll
            for (int ss = 0; ss < 4; ++ss) {
                const int tcur = tca[ss];
                const uint2 zcur = zxp[ss];

                // ---- pre-barrier: publish h (1 cvt + 1 ds_write) ----
                hl[ss & 1][quad * 4][u] = (unsigned short)cvtpk_bf16(h_st, h_st);

                // acc z-inits ride the barrier wait
                accA[0][0] = bflo2f(zcur.x);
                accA[1][0] = bfhi2f(zcur.x);
                accA[2][0] = bflo2f(zcur.y);
                accA[3][0] = bfhi2f(zcur.y);

                block_sync_lds();

                const unsigned short* hrow = &hl[ss & 1][l16][0];
                short8 a0 = *(const short8*)(hrow + quad * 8);
                short8 a1 = *(const short8*)(hrow + 32 + quad * 8);

                // off-chain: prefetch z for t = sb+ss+4 (addr math fills
                // the lgkm wait shadow before the MFMAs)
                zxp[ss] = *(const uint2*)(ebase + tnx[ss]);

                // issue g=2 (cell, longest gate chain) first, then i, f, o
                accA[2] = __builtin_amdgcn_mfma_f32_16x16x32_bf16(a0, bU[2][0], accA[2], 0, 0, 0);
                accB[2] = __builtin_amdgcn_mfma_f32_16x16x32_bf16(a1, bU[2][1], zz, 0, 0, 0);
                accA[0] = __builtin_amdgcn_mfma_f32_16x16x32_bf16(a0, bU[0][0], accA[0], 0, 0, 0);
                accB[0] = __builtin_amdgcn_mfma_f32_16x16x32_bf16(a1, bU[0][1], zz, 0, 0, 0);
                accA[1] = __builtin_amdgcn_mfma_f32_16x16x32_bf16(a0, bU[1][0], accA[1], 0, 0, 0);
                accB[1] = __builtin_amdgcn_mfma_f32_16x16x32_bf16(a1, bU[1][1], zz, 0, 0, 0);
                accA[3] = __builtin_amdgcn_mfma_f32_16x16x32_bf16(a0, bU[3][0], accA[3], 0, 0, 0);
                accB[3] = __builtin_amdgcn_mfma_f32_16x16x32_bf16(a1, bU[3][1], zz, 0, 0, 0);

                {
                    float zg_ = accA[2][0] + accB[2][0];
                    float tg  = tanh_(zg_);
                    float zi_ = accA[0][0] + accB[0][0];
                    float si  = sigm(zi_);
                    float zf_ = accA[1][0] + accB[1][0];
                    float zo_ = accA[3][0] + accB[3][0];
                    float cn  = sigm(zf_) * c_st + si * tg;
                    float hn  = sigm(zo_) * tanh_(cn);
                    bool m = (tcur != 0);
                    h_st = m ? hn : h_st;
                    c_st = m ? cn : c_st;
                }
            }
            tca = tnx;
        }
        __builtin_amdgcn_s_setprio(0);

        // publish h_511 for the pot wave's final step (s=512 -> buffer 0)
        hl[0][quad * 4][u] = (unsigned short)cvtpk_bf16(h_st, h_st);
        block_sync_lds();
    } else {
        // ================= pot wave =================
        short8 bW[2];
#pragma unroll
        for (int q = 0; q < 2; ++q) {
            short8 v;
#pragma unroll
            for (int j = 0; j < 8; ++j) {
                int k = q * 32 + quad * 8 + j;
                v[j] = (l16 < KK) ? (short)f2bf(Wd[(dir * 64 + k) * KK + l16]) : (short)0;
            }
            bW[q] = v;
        }

        __syncthreads();

        int vOff = ((row0 + quad) * TT + (dir ? (TT - 1) : 0)) * KK + l16;
        const int vStep = dir ? -KK : KK;
        const bool potAct = (l16 < KK);
        const float4v zz = {0.f, 0.f, 0.f, 0.f};

        for (int s = 0; s <= TT; ++s) {
            block_sync_lds();
            const unsigned short* hrow = &hl[s & 1][l16][0];
            short8 a0 = *(const short8*)(hrow + quad * 8);
            short8 a1 = *(const short8*)(hrow + 32 + quad * 8);
            if (s > 0) {
                float4v accP;
                accP = __builtin_amdgcn_mfma_f32_16x16x32_bf16(a0, bW[0], zz, 0, 0, 0);
                accP = __builtin_amdgcn_mfma_f32_16x16x32_bf16(a1, bW[1], accP, 0, 0, 0);
                if (potAct) pot[vOff] = accP[0];
                vOff += vStep;
            }
        }
    }
}

// ---------------------------------------------------------------------------
// Fused combine + Viterbi (64-thread proven version). readlane broadcast +
// max3 value-max + equality cascade; padded LDS kills the t+1 guard.
// ---------------------------------------------------------------------------
__global__ __launch_bounds__(64)
void viterbi_kernel(const int* __restrict__ tokens,
                    const float* __restrict__ potf, const float* __restrict__ potb,
                    const float* __restrict__ bd, const float* __restrict__ trans,
                    float* __restrict__ dec_out, float* __restrict__ pot_out,
                    float* __restrict__ seq_out)
{
    const int row = blockIdx.x;
    const int lane = threadIdx.x;

    __shared__ float pl[TT * KK + 16];      // padded: t+1 == TT read is safe
    __shared__ unsigned char bpl[(TT - 1) * KK];
    __shared__ unsigned char maskl[TT + 8]; // padded
    __shared__ unsigned char segmap[64][KK];
    __shared__ unsigned char bseq[65];
    __shared__ float decl_[TT];
    __shared__ float bdl[16];

    if (lane < KK) bdl[lane] = bd[lane];
    if (lane < 8) maskl[TT + lane] = 0;
    pl[TT * KK + lane % 16] = 0.f;

    int cnt = 0;
#pragma unroll
    for (int ch = 0; ch < TT / 64; ++ch) {
        int tk = tokens[row * TT + ch * 64 + lane];
        int m = (tk != 0) ? 1 : 0;
        maskl[ch * 64 + lane] = (unsigned char)m;
        cnt += m;
    }
    for (int off = 32; off > 0; off >>= 1) cnt += __shfl_down(cnt, off);
    if (lane == 0) seq_out[row] = (float)cnt;

    const size_t base = (size_t)row * (TT * KK);
    int r9 = lane % KK;
    for (int i = 0; i < (TT * KK) / 64; ++i) {
        int li = i * 64 + lane;
        float s = potf[base + li] + potb[base + li] + bdl[r9];
        pl[li] = s;
        pot_out[base + li] = s;
        r9 = (r9 + 1 == KK) ? 0 : r9 + 1;
    }
    __syncthreads();

    float treg[KK];
#pragma unroll
    for (int i = 0; i < KK; ++i) treg[i] = (lane < KK) ? trans[i * KK + lane] : 0.f;

    float alpha = (lane < KK) ? pl[lane] : -1e30f;
    float pnext = (lane < KK) ? pl[KK + lane] : 0.f;
    int mnext = maskl[1];
#pragma unroll 4
    for (int t = 1; t < TT; ++t) {
        float p = pnext;
        int m = mnext;
        pnext = (lane < KK) ? pl[(t + 1) * KK + lane] : 0.f;  // pad makes t+1==TT safe
        mnext = maskl[t + 1];

        float sc[KK];
#pragma unroll
        for (int i = 0; i < KK; ++i) sc[i] = bcast(alpha, i) + treg[i];
        float b0 = fmaxf(fmaxf(fmaxf(sc[0], sc[1]), sc[2]),
                   fmaxf(fmaxf(fmaxf(sc[3], sc[4]), sc[5]),
                         fmaxf(fmaxf(sc[6], sc[7]), sc[8])));
        int i0 = 8;
#pragma unroll
        for (int i = 7; i >= 0; --i) i0 = (sc[i] == b0) ? i : i0;

        alpha = m ? (b0 + p) : alpha;
        int bpv = m ? i0 : lane;
        if (lane < KK) bpl[(t - 1) * KK + lane] = (unsigned char)bpv;
    }
    float sc[KK];
#pragma unroll
    for (int i = 0; i < KK; ++i) sc[i] = bcast(alpha, i);
    float b0 = fmaxf(fmaxf(fmaxf(sc[0], sc[1]), sc[2]),
               fmaxf(fmaxf(fmaxf(sc[3], sc[4]), sc[5]),
                     fmaxf(fmaxf(sc[6], sc[7]), sc[8])));
    int last = 8;
#pragma unroll
    for (int i = 7; i >= 0; --i) last = (sc[i] == b0) ? i : last;
    __syncthreads();

    {
        int l = lane;
#pragma unroll
        for (int x = 0; x < KK; ++x) {
            int y = x;
#pragma unroll
            for (int d = 7; d >= 0; --d) {
                int t = 8 * l + d;
                if (t < TT - 1) y = bpl[t * KK + y];
            }
            segmap[l][x] = (unsigned char)y;
        }
    }
    __syncthreads();
    if (lane == 0) {
        int cur = last;
        bseq[64] = (unsigned char)last;
        for (int l = 63; l >= 0; --l) {
            cur = segmap[l][cur];
            bseq[l] = (unsigned char)cur;
        }
    }
    __syncthreads();
    {
        int l = lane;
        int cur = bseq[l + 1];
#pragma unroll
        for (int d = 7; d >= 0; --d) {
            int t = 8 * l + d;
            if (t < TT - 1) cur = bpl[t * KK + cur];
            decl_[t] = (maskl[t] != 0) ? (float)cur : 0.f;
        }
    }
    __syncthreads();
#pragma unroll
    for (int ch = 0; ch < TT / 64; ++ch)
        dec_out[(size_t)row * TT + ch * 64 + lane] = decl_[ch * 64 + lane];
}

extern "C" void kernel_launch(void* const* d_in, const int* in_sizes, int n_in,
                              void* d_out, int out_size, void* d_ws, size_t ws_size,
                              hipStream_t stream)
{
    const int*   tokens = (const int*)d_in[0];
    const float* emb    = (const float*)d_in[1];
    const float* Wf     = (const float*)d_in[2];
    const float* Uf     = (const float*)d_in[3];
    const float* bfv    = (const float*)d_in[4];
    const float* Wb     = (const float*)d_in[5];
    const float* Ub     = (const float*)d_in[6];
    const float* bbv    = (const float*)d_in[7];
    const float* Wd     = (const float*)d_in[8];
    const float* bd     = (const float*)d_in[9];
    const float* trans  = (const float*)d_in[10];

    float* out     = (float*)d_out;
    float* dec_out = out;
    float* pot_out = out + (size_t)BB * TT;
    float* seq_out = out + (size_t)BB * TT + BTK;

    float* potf = (float*)d_ws;
    float* potb = potf + BTK;
    unsigned short* embw = (unsigned short*)(potb + BTK);
    // wswz/bsw alias the potf region: consumed by embw_kernel BEFORE rec_kernel
    // writes potf (stream-ordered), so no extra workspace needed.
    unsigned short* wswz = (unsigned short*)potf;
    float* bsw = (float*)((char*)potf + 512 * 64 * sizeof(unsigned short));

    hipLaunchKernelGGL(wswz_kernel, dim3(8), dim3(256), 0, stream,
                       Wf, bfv, Wb, bbv, wswz, bsw);
    hipLaunchKernelGGL(embw_kernel, dim3(469), dim3(256), 0, stream,
                       emb, wswz, bsw, embw);
    hipLaunchKernelGGL(rec_kernel, dim3(256), dim3(320), 0, stream,
                       tokens, embw, Uf, Ub, Wd, potf, potb);
    hipLaunchKernelGGL(viterbi_kernel, dim3(BB), dim3(64), 0, stream,
                       tokens, potf, potb, bd, trans, dec_out, pot_out, seq_out);
}